// Round 1
// baseline (185.732 us; speedup 1.0000x reference)
//
#include <hip/hip_runtime.h>
#include <hip/hip_bf16.h>

// MaskFiller scatter:
//   out[b, keep_ids[b,k], :] = inputs[b,k,:]
//   out[b, mask_ids[b,m], :] = mask_embedding[:]
// B=8, K=4096, M=4096, L=8192, D=512 (fp32).
// keep+mask ids partition [0,L) per batch -> every row written exactly once.

constexpr int B = 8;
constexpr int K = 4096;
constexpr int M = 4096;
constexpr int L = K + M;   // 8192
constexpr int D = 512;
constexpr int D4 = D / 4;  // 128 float4 per row

__global__ __launch_bounds__(128)
void MaskFiller_scatter_kernel(const float4* __restrict__ inputs,
                               const int* __restrict__ mask_ids,
                               const int* __restrict__ keep_ids,
                               const float4* __restrict__ emb,
                               float4* __restrict__ out) {
    const int row = blockIdx.x;      // [0, B*L)
    const int b   = row / L;
    const int r   = row - b * L;     // [0, L)
    const int d4  = threadIdx.x;     // [0, 128)

    float4 v;
    int dst;
    if (r < K) {
        // keep row: copy from inputs
        dst = keep_ids[b * K + r];
        v   = inputs[(size_t)(b * K + r) * D4 + d4];
    } else {
        // mask row: broadcast embedding
        const int m = r - K;
        dst = mask_ids[b * M + m];
        v   = emb[d4];
    }
    out[((size_t)b * L + dst) * D4 + d4] = v;
}

extern "C" void kernel_launch(void* const* d_in, const int* in_sizes, int n_in,
                              void* d_out, int out_size, void* d_ws, size_t ws_size,
                              hipStream_t stream) {
    const float4* inputs   = (const float4*)d_in[0];
    const int*    mask_ids = (const int*)d_in[1];
    const int*    keep_ids = (const int*)d_in[2];
    const float4* emb      = (const float4*)d_in[3];
    // d_in[4] is `axis` (-2), unused.
    float4* out = (float4*)d_out;

    dim3 grid(B * L);   // 65536 blocks, one per output row
    dim3 block(128);    // 128 threads x float4 = 2048 B = one row
    MaskFiller_scatter_kernel<<<grid, block, 0, stream>>>(inputs, mask_ids, keep_ids, emb, out);
}